// Round 7
// baseline (325.455 us; speedup 1.0000x reference)
//
#include <hip/hip_runtime.h>

// PosteriorHiddenTreeMarkovModel — MI355X / gfx950
// R7: single fused kernel with MANUAL grid barrier (cooperative launch breaks
// the harness's graph capture — R6 never dispatched).
// Co-residency proof: LDS 64.3 KB -> 2 blocks/CU x 256 CU = 512 >= 432 blocks,
// so all blocks are resident and the spin barrier cannot deadlock. Barrier:
// block0 zeroes 3 one-shot counters, release-stores MAGIC flag; all blocks
// acquire-spin on flag (init-agnostic vs ws poison), then each barrier =
// threadfence + device-scope atomicAdd + acquire-spin to 432 (+ spin cap).
// LDS subtree state persists across phases -> no up-replay.
// Phases: 0 params (block0 writes Bm->global) | 1 subtree up (writes b3)
// | 2 mid levels 0-3 by 64 q==0 waves (writes e3 + out) | 3 subtree down.

namespace {

constexpr int kNPT = 3280;
constexpr int kRS  = 72;   // record stride: 64 beta + 8 pre-norm sums s
constexpr unsigned kMAGIC = 0x13579BDFu;
constexpr unsigned kNBLK  = 432;
__device__ __constant__ int LO[6] = {0, 1, 4, 13, 40, 121};
__device__ __constant__ int P3[5] = {1, 3, 9, 27, 81};

__device__ __forceinline__ void leaf_beta(const float* __restrict__ sPi,
                                          const float* __restrict__ pBm,
                                          int p, int xv, int g, float* b)
{
    float s = 0.f;
    #pragma unroll
    for (int c = 0; c < 8; ++c) {
        b[c] = sPi[(c * 3 + p) * 8 + g] * pBm[xv * 64 + c * 8 + g];
        s += b[c];
    }
    float ig = __builtin_amdgcn_rcpf(s);
    #pragma unroll
    for (int c = 0; c < 8; ++c) b[c] *= ig;
}

__device__ __forceinline__ void gbar(unsigned* c, int tid)
{
    __syncthreads();
    if (tid == 0) {
        __threadfence();                       // release: flush this XCD's L2
        atomicAdd(c, 1u);                      // device-scope RMW
        unsigned long sp = 0;
        while (__hip_atomic_load(c, __ATOMIC_ACQUIRE, __HIP_MEMORY_SCOPE_AGENT) < kNBLK) {
            if (++sp > (1UL << 27)) break;     // hang guard
            __builtin_amdgcn_s_sleep(2);
        }
        __threadfence();                       // acquire reinforcement
    }
    __syncthreads();
}

__global__ __launch_bounds__(256, 2)
void fused(const float* __restrict__ lamA, const float* __restrict__ lamB,
           const float* __restrict__ lamPi, const float* __restrict__ lamSP,
           const int* __restrict__ x, float* __restrict__ out,
           unsigned* __restrict__ sync, float* __restrict__ bmG,
           float* __restrict__ b3, float* __restrict__ e3)
{
    const int tid = threadIdx.x, w = tid >> 6, lane = tid & 63;
    const int n = lane >> 3, g = lane & 7;
    __shared__ float sA[1536], sALA[1536], sPi[192], sLPi[192], sSP[24], sLSP[24];
    __shared__ float bW[4][40 * kRS];      // per-wave subtree records
    __shared__ float bMid[13 * kRS];       // mid-wave records (<=1 mid wave/block)
    __shared__ unsigned char xW[4][124];

    // ---- init gate: block0 zeroes counters, release-stores flag ----
    if (tid == 0) {
        if (blockIdx.x == 0) {
            sync[1] = 0u; sync[2] = 0u; sync[3] = 0u;
            __threadfence();
            __hip_atomic_store(&sync[0], kMAGIC, __ATOMIC_RELEASE, __HIP_MEMORY_SCOPE_AGENT);
        }
        unsigned long sp = 0;
        while (__hip_atomic_load(&sync[0], __ATOMIC_ACQUIRE, __HIP_MEMORY_SCOPE_AGENT) != kMAGIC) {
            if (++sp > (1UL << 27)) break;
            __builtin_amdgcn_s_sleep(2);
        }
    }
    __syncthreads();

    // ================= phase 0: parameters =================
    for (int col = tid; col < 192; col += 256) {          // A softmax over i
        int j = col / 24; int rem = col - j * 24; int p = rem >> 3; int gg = rem & 7;
        float v[8]; float mx = -1e30f;
        #pragma unroll
        for (int i = 0; i < 8; ++i) {
            v[i] = lamA[((i * 8 + j) * 3 + p) * 8 + gg];
            mx = fmaxf(mx, v[i]);
        }
        float s = 0.f;
        #pragma unroll
        for (int i = 0; i < 8; ++i) { v[i] = expf(v[i] - mx); s += v[i]; }
        float inv = 1.f / s;
        #pragma unroll
        for (int i = 0; i < 8; ++i) {
            int idx = ((i * 8 + j) * 3 + p) * 8 + gg;
            float sm = v[i] * inv;
            sA[idx]   = sm;
            sALA[idx] = sm * logf(sm);
        }
    }
    for (int col = tid; col < 24; col += 256) {           // Pi softmax over c
        int p = col >> 3; int gg = col & 7;
        float v[8]; float mx = -1e30f;
        #pragma unroll
        for (int c = 0; c < 8; ++c) {
            v[c] = lamPi[(c * 3 + p) * 8 + gg];
            mx = fmaxf(mx, v[c]);
        }
        float s = 0.f;
        #pragma unroll
        for (int c = 0; c < 8; ++c) { v[c] = expf(v[c] - mx); s += v[c]; }
        float inv = 1.f / s;
        #pragma unroll
        for (int c = 0; c < 8; ++c) {
            int idx = (c * 3 + p) * 8 + gg;
            float sm = v[c] * inv;
            sPi[idx]  = sm;
            sLPi[idx] = logf(sm);
        }
    }
    if (tid < 8) {                                        // SP softmax over p
        int gg = tid;
        float v0 = lamSP[gg], v1 = lamSP[8 + gg], v2 = lamSP[16 + gg];
        float mx = fmaxf(v0, fmaxf(v1, v2));
        float e0 = expf(v0 - mx), e1 = expf(v1 - mx), e2 = expf(v2 - mx);
        float inv = 1.f / (e0 + e1 + e2);
        sSP[gg] = e0 * inv; sSP[8 + gg] = e1 * inv; sSP[16 + gg] = e2 * inv;
        sLSP[gg] = logf(e0 * inv); sLSP[8 + gg] = logf(e1 * inv); sLSP[16 + gg] = logf(e2 * inv);
    }
    {   // Bm softmax (block 0 computes + writes bmG transposed [m][c][g])
        float* rr = &bW[0][0];                            // scratch alias
        int row = tid >> 2, part = tid & 3;
        int c = row >> 3, gg = row & 7, m0 = part * 32;
        float mx = -1e30f;
        if (blockIdx.x == 0)
            for (int mm = 0; mm < 32; ++mm)
                mx = fmaxf(mx, lamB[(c * 128 + m0 + mm) * 8 + gg]);
        rr[tid] = mx;
        __syncthreads();
        float m4 = fmaxf(fmaxf(rr[row * 4], rr[row * 4 + 1]),
                         fmaxf(rr[row * 4 + 2], rr[row * 4 + 3]));
        float s = 0.f;
        if (blockIdx.x == 0)
            for (int mm = 0; mm < 32; ++mm)
                s += expf(lamB[(c * 128 + m0 + mm) * 8 + gg] - m4);
        rr[256 + tid] = s;
        __syncthreads();
        if (blockIdx.x == 0) {
            float stot = rr[256 + row * 4] + rr[256 + row * 4 + 1]
                       + rr[256 + row * 4 + 2] + rr[256 + row * 4 + 3];
            float inv = 1.f / stot;
            for (int mm = 0; mm < 32; ++mm)
                bmG[(m0 + mm) * 64 + c * 8 + gg] =
                    expf(lamB[(c * 128 + m0 + mm) * 8 + gg] - m4) * inv;
        }
    }
    gbar(&sync[1], tid);

    const float* pBm = bmG;
    const int id = blockIdx.x * 4 + w, t = id / 27, q = id % 27, xb = t * kNPT;
    float* bw = &bW[w][0];
    unsigned char* xw = &xW[w][0];

    // ================= phase 1: subtree up-pass =================
    for (int u = lane; u < 121; u += 64) {
        int gx;
        if (u == 0)       gx = 13 + q;
        else if (u < 4)   gx = 40  + q * 3  + (u - 1);
        else if (u < 13)  gx = 121 + q * 9  + (u - 4);
        else if (u < 40)  gx = 364 + q * 27 + (u - 13);
        else              gx = 1093 + q * 81 + (u - 40);
        xw[u] = (unsigned char)x[xb + gx];
    }
    __builtin_amdgcn_wave_barrier();

    for (int e = 3; e >= 0; --e) {
        int cnt = P3[e];
        for (int base = 0; base < cnt; base += 8) {
            int pi = base + n;
            if (pi < cnt) {
                float acc[8];
                #pragma unroll
                for (int i = 0; i < 8; ++i) acc[i] = 0.f;
                #pragma unroll
                for (int k = 0; k < 3; ++k) {
                    float bj[8];
                    if (e == 3) {
                        leaf_beta(sPi, pBm, k, xw[40 + 3 * pi + k], g, bj);
                    } else {
                        int co = (LO[e + 1] + 3 * pi + k) * kRS + g;
                        #pragma unroll
                        for (int j = 0; j < 8; ++j) bj[j] = bw[co + j * 8];
                    }
                    float spg = sSP[k * 8 + g];
                    #pragma unroll
                    for (int i = 0; i < 8; ++i) {
                        float s = 0.f;
                        #pragma unroll
                        for (int j = 0; j < 8; ++j)
                            s = fmaf(sA[((i * 8 + j) * 3 + k) * 8 + g], bj[j], s);
                        acc[i] = fmaf(spg, s, acc[i]);
                    }
                }
                if (e == 0) {
                    #pragma unroll
                    for (int i = 0; i < 8; ++i) bw[i * 8 + g] = acc[i];  // raw tb root
                    int xv = xw[0];
                    float s = 0.f;
                    #pragma unroll
                    for (int i = 0; i < 8; ++i) { acc[i] *= pBm[xv * 64 + i * 8 + g]; s += acc[i]; }
                    float ig = __builtin_amdgcn_rcpf(s);
                    #pragma unroll
                    for (int i = 0; i < 8; ++i) b3[id * 64 + i * 8 + g] = acc[i] * ig;
                } else {
                    int slot = LO[e] + pi;
                    int xv = xw[slot];
                    float s = 0.f;
                    #pragma unroll
                    for (int i = 0; i < 8; ++i) { acc[i] *= pBm[xv * 64 + i * 8 + g]; s += acc[i]; }
                    float ig = __builtin_amdgcn_rcpf(s);
                    int bo = slot * kRS + g;
                    #pragma unroll
                    for (int i = 0; i < 8; ++i) bw[bo + i * 8] = acc[i] * ig;
                    bw[slot * kRS + 64 + g] = s;
                }
            }
        }
        __builtin_amdgcn_wave_barrier();
    }
    gbar(&sync[2], tid);

    // ================= phase 2: mid (levels 0-3), one wave per tree ==========
    if (q == 0) {
        float ellm = 0.f;
        for (int f = 2; f >= 0; --f) {
            int cnt = (f == 2) ? 9 : (f == 1 ? 3 : 1);
            int pl0 = (f == 2) ? 4 : (f == 1 ? 1 : 0);
            int cl0 = (f == 1) ? 4 : 1;
            for (int base = 0; base < cnt; base += 8) {
                int pi = base + n;
                if (pi < cnt) {
                    float acc[8];
                    #pragma unroll
                    for (int i = 0; i < 8; ++i) acc[i] = 0.f;
                    #pragma unroll
                    for (int k = 0; k < 3; ++k) {
                        float bj[8];
                        if (f == 2) {
                            const float* src = b3 + (t * 27 + 3 * pi + k) * 64 + g;
                            #pragma unroll
                            for (int j = 0; j < 8; ++j) bj[j] = src[j * 8];
                        } else {
                            int co = (cl0 + 3 * pi + k) * kRS + g;
                            #pragma unroll
                            for (int j = 0; j < 8; ++j) bj[j] = bMid[co + j * 8];
                        }
                        float spg = sSP[k * 8 + g];
                        #pragma unroll
                        for (int i = 0; i < 8; ++i) {
                            float s = 0.f;
                            #pragma unroll
                            for (int j = 0; j < 8; ++j)
                                s = fmaf(sA[((i * 8 + j) * 3 + k) * 8 + g], bj[j], s);
                            acc[i] = fmaf(spg, s, acc[i]);
                        }
                    }
                    int slot = pl0 + pi;
                    int xv = x[xb + slot];
                    float s = 0.f;
                    #pragma unroll
                    for (int i = 0; i < 8; ++i) { acc[i] *= pBm[xv * 64 + i * 8 + g]; s += acc[i]; }
                    float ig = __builtin_amdgcn_rcpf(s);
                    int bo = slot * kRS + g;
                    #pragma unroll
                    for (int i = 0; i < 8; ++i) bMid[bo + i * 8] = acc[i] * ig;
                    bMid[slot * kRS + 64 + g] = s;
                }
            }
            __builtin_amdgcn_wave_barrier();
        }
        if (n == 0) {     // root: ell Bm term; slot0 := r = Bm/s
            int xv = x[xb];
            float invs = __builtin_amdgcn_rcpf(bMid[64 + g]);
            #pragma unroll
            for (int c = 0; c < 8; ++c)
                ellm += bMid[c * 8 + g] * pBm[xv * 64 + c * 8 + g];
            #pragma unroll
            for (int c = 0; c < 8; ++c)
                bMid[c * 8 + g] = pBm[xv * 64 + c * 8 + g] * invs;
        }
        __builtin_amdgcn_wave_barrier();
        for (int f = 1; f <= 3; ++f) {
            int cnt = (f == 1) ? 3 : (f == 2 ? 9 : 27);
            int cl0 = (f == 1) ? 1 : (f == 2 ? 4 : 13);
            int pl0 = (f == 1) ? 0 : (f == 2 ? 1 : 4);
            for (int base = 0; base < cnt; base += 8) {
                int ci = base + n;
                if (ci < cnt) {
                    int p = ci % 3;
                    int ps = (pl0 + ci / 3) * kRS + g;
                    float r[8];
                    #pragma unroll
                    for (int i = 0; i < 8; ++i) r[i] = bMid[ps + i * 8];
                    float bj[8]; float sv = 0.f;
                    if (f == 3) {
                        const float* src = b3 + (t * 27 + ci) * 64 + g;
                        #pragma unroll
                        for (int j = 0; j < 8; ++j) bj[j] = src[j * 8];
                    } else {
                        int co = (cl0 + ci) * kRS + g;
                        #pragma unroll
                        for (int j = 0; j < 8; ++j) bj[j] = bMid[co + j * 8];
                        sv = bMid[(cl0 + ci) * kRS + 64 + g];
                    }
                    float spg = sSP[p * 8 + g];
                    float esum = 0.f, lg = 0.f;
                    float ev[8];
                    #pragma unroll
                    for (int j = 0; j < 8; ++j) {
                        float s1 = 0.f, s2 = 0.f;
                        #pragma unroll
                        for (int i = 0; i < 8; ++i) {
                            int ai = ((i * 8 + j) * 3 + p) * 8 + g;
                            s1 = fmaf(r[i], sA[ai],   s1);
                            s2 = fmaf(r[i], sALA[ai], s2);
                        }
                        float bs = spg * bj[j];
                        ev[j] = bs * s1;
                        lg    = fmaf(bs, s2, lg);
                        esum += ev[j];
                    }
                    lg = fmaf(esum, sLSP[p * 8 + g], lg);
                    int xv = x[xb + cl0 + ci];
                    float Bmv[8];
                    #pragma unroll
                    for (int c = 0; c < 8; ++c) {
                        Bmv[c] = pBm[xv * 64 + c * 8 + g];
                        lg = fmaf(ev[c], Bmv[c], lg);
                    }
                    if (f == 3) {
                        #pragma unroll
                        for (int j = 0; j < 8; ++j)
                            e3[(t * 27 + ci) * 64 + j * 8 + g] = ev[j];
                    } else {
                        int co = (cl0 + ci) * kRS + g;
                        #pragma unroll
                        for (int j = 0; j < 8; ++j)
                            bMid[co + j * 8] = ev[j] * Bmv[j]
                                * __builtin_amdgcn_rcpf(bj[j] * sv);
                    }
                    ellm += lg;
                }
            }
            __builtin_amdgcn_wave_barrier();
        }
        ellm += __shfl_xor(ellm, 8);
        ellm += __shfl_xor(ellm, 16);
        ellm += __shfl_xor(ellm, 32);
        if (n == 0) out[t * 8 + g] = -ellm;      // initializes poisoned out
    }
    gbar(&sync[3], tid);

    // ================= phase 3: subtree down-pass =================
    bw[lane] = e3[id * 64 + lane] * __builtin_amdgcn_rcpf(bw[lane]);  // root r
    __builtin_amdgcn_wave_barrier();

    float ell = 0.f;
    for (int e = 1; e <= 4; ++e) {
        int cnt = P3[e], pl0 = LO[e - 1];
        for (int base = 0; base < cnt; base += 8) {
            int ci = base + n;
            if (ci < cnt) {
                int p = ci % 3;
                int ps = (pl0 + ci / 3) * kRS + g;
                float r[8];
                #pragma unroll
                for (int i = 0; i < 8; ++i) r[i] = bw[ps + i * 8];
                float bj[8]; float sv = 0.f;
                int xv;
                if (e == 4) {
                    xv = xw[40 + ci];
                    leaf_beta(sPi, pBm, p, xv, g, bj);
                } else {
                    int slot = LO[e] + ci;
                    xv = xw[slot];
                    int co = slot * kRS + g;
                    #pragma unroll
                    for (int j = 0; j < 8; ++j) bj[j] = bw[co + j * 8];
                    sv = bw[slot * kRS + 64 + g];
                }
                float spg = sSP[p * 8 + g];
                float esum = 0.f, lg = 0.f;
                float ev[8];
                #pragma unroll
                for (int j = 0; j < 8; ++j) {
                    float s1 = 0.f, s2 = 0.f;
                    #pragma unroll
                    for (int i = 0; i < 8; ++i) {
                        int ai = ((i * 8 + j) * 3 + p) * 8 + g;
                        s1 = fmaf(r[i], sA[ai],   s1);
                        s2 = fmaf(r[i], sALA[ai], s2);
                    }
                    float bs = spg * bj[j];
                    ev[j] = bs * s1;
                    lg    = fmaf(bs, s2, lg);
                    esum += ev[j];
                }
                lg = fmaf(esum, sLSP[p * 8 + g], lg);
                float Bmv[8];
                #pragma unroll
                for (int c = 0; c < 8; ++c) {
                    Bmv[c] = pBm[xv * 64 + c * 8 + g];
                    lg = fmaf(ev[c], Bmv[c], lg);
                }
                if (e < 4) {
                    int slot = LO[e] + ci;
                    int co = slot * kRS + g;
                    #pragma unroll
                    for (int j = 0; j < 8; ++j)
                        bw[co + j * 8] = ev[j] * Bmv[j]
                            * __builtin_amdgcn_rcpf(bj[j] * sv);
                } else {
                    #pragma unroll
                    for (int c = 0; c < 8; ++c)
                        lg = fmaf(ev[c], sLPi[(c * 3 + p) * 8 + g], lg);
                }
                ell += lg;
            }
        }
        __builtin_amdgcn_wave_barrier();
    }

    ell += __shfl_xor(ell, 8);
    ell += __shfl_xor(ell, 16);
    ell += __shfl_xor(ell, 32);
    if (n == 0) atomicAdd(&out[t * 8 + g], -ell);
}

} // namespace

extern "C" void kernel_launch(void* const* d_in, const int* in_sizes, int n_in,
                              void* d_out, int out_size, void* d_ws, size_t ws_size,
                              hipStream_t stream) {
    const float* lamA  = (const float*)d_in[0];
    const float* lamB  = (const float*)d_in[1];
    const float* lamPi = (const float*)d_in[2];
    const float* lamSP = (const float*)d_in[3];
    const int*   x     = (const int*)d_in[4];
    float* out = (float*)d_out;
    unsigned* sync = (unsigned*)d_ws;       // [0]=flag, [1..3]=barrier counters
    float* bmG = (float*)d_ws + 16;         // 8192 floats
    float* b3  = bmG + 8192;                // 1728*64
    float* e3  = b3 + 1728 * 64;            // 1728*64

    fused<<<dim3(432), dim3(256), 0, stream>>>(
        lamA, lamB, lamPi, lamSP, x, out, sync, bmG, b3, e3);
}

// Round 8
// 235.132 us; speedup vs baseline: 1.3841x; 1.3841x over previous
//
#include <hip/hip_runtime.h>

// PosteriorHiddenTreeMarkovModel — MI355X / gfx950
// R8: R7 fused kernel + barrier fix. R7's spin polled with ACQUIRE agent-scope
// loads -> buffer_inv (L1+L2 invalidate) EVERY poll iteration x ~430 blocks =
// invalidation storm that stretched every barrier tail to ~70us (VALUBusy 7%).
// Fix: poll with RELAXED agent loads (coherent, no invalidate), single
// __threadfence() after spin exit for acquire ordering; s_sleep(4) throttle;
// sync words moved 2KB away from bmG (no cache-line sharing with hot reads);
// block0 computes Bm first in phase 0.
// Co-residency: LDS 63KB -> 2 blocks/CU x 256 = 512 >= 432 blocks.

namespace {

constexpr int kNPT = 3280;
constexpr int kRS  = 72;   // record stride: 64 beta + 8 pre-norm sums s
constexpr unsigned kMAGIC = 0x13579BDFu;
constexpr unsigned kNBLK  = 432;
__device__ __constant__ int LO[6] = {0, 1, 4, 13, 40, 121};
__device__ __constant__ int P3[5] = {1, 3, 9, 27, 81};

__device__ __forceinline__ void leaf_beta(const float* __restrict__ sPi,
                                          const float* __restrict__ pBm,
                                          int p, int xv, int g, float* b)
{
    float s = 0.f;
    #pragma unroll
    for (int c = 0; c < 8; ++c) {
        b[c] = sPi[(c * 3 + p) * 8 + g] * pBm[xv * 64 + c * 8 + g];
        s += b[c];
    }
    float ig = __builtin_amdgcn_rcpf(s);
    #pragma unroll
    for (int c = 0; c < 8; ++c) b[c] *= ig;
}

__device__ __forceinline__ void gbar(unsigned* c, int tid)
{
    __syncthreads();
    if (tid == 0) {
        __threadfence();                       // release: wb this XCD's L2
        atomicAdd(c, 1u);                      // device-scope RMW
        unsigned long sp = 0;
        while (__hip_atomic_load(c, __ATOMIC_RELAXED, __HIP_MEMORY_SCOPE_AGENT) < kNBLK) {
            if (++sp > (1UL << 24)) break;     // hang guard
            __builtin_amdgcn_s_sleep(4);
        }
        __threadfence();                       // ONE acquire invalidate
    }
    __syncthreads();
}

__global__ __launch_bounds__(256, 2)
void fused(const float* __restrict__ lamA, const float* __restrict__ lamB,
           const float* __restrict__ lamPi, const float* __restrict__ lamSP,
           const int* __restrict__ x, float* __restrict__ out,
           unsigned* __restrict__ sync, float* __restrict__ bmG,
           float* __restrict__ b3, float* __restrict__ e3)
{
    const int tid = threadIdx.x, w = tid >> 6, lane = tid & 63;
    const int n = lane >> 3, g = lane & 7;
    __shared__ float sA[1536], sALA[1536], sPi[192], sLPi[192], sSP[24], sLSP[24];
    __shared__ float bW[4][40 * kRS];      // per-wave subtree records
    __shared__ float bMid[13 * kRS];       // mid-wave records (<=1 mid wave/block)
    __shared__ unsigned char xW[4][124];

    // ---- init gate: block0 zeroes counters, publishes flag ----
    if (tid == 0) {
        if (blockIdx.x == 0) {
            sync[1] = 0u; sync[2] = 0u; sync[3] = 0u;
            __threadfence();
            __hip_atomic_store(&sync[0], kMAGIC, __ATOMIC_RELAXED, __HIP_MEMORY_SCOPE_AGENT);
        }
        unsigned long sp = 0;
        while (__hip_atomic_load(&sync[0], __ATOMIC_RELAXED, __HIP_MEMORY_SCOPE_AGENT) != kMAGIC) {
            if (++sp > (1UL << 24)) break;
            __builtin_amdgcn_s_sleep(4);
        }
        __threadfence();
    }
    __syncthreads();

    // ================= phase 0: parameters =================
    {   // Bm softmax FIRST (block 0 computes + writes bmG transposed [m][c][g])
        float* rr = &bW[0][0];                            // scratch alias
        int row = tid >> 2, part = tid & 3;
        int c = row >> 3, gg = row & 7, m0 = part * 32;
        float mx = -1e30f;
        if (blockIdx.x == 0)
            for (int mm = 0; mm < 32; ++mm)
                mx = fmaxf(mx, lamB[(c * 128 + m0 + mm) * 8 + gg]);
        rr[tid] = mx;
        __syncthreads();
        float m4 = fmaxf(fmaxf(rr[row * 4], rr[row * 4 + 1]),
                         fmaxf(rr[row * 4 + 2], rr[row * 4 + 3]));
        float s = 0.f;
        if (blockIdx.x == 0)
            for (int mm = 0; mm < 32; ++mm)
                s += expf(lamB[(c * 128 + m0 + mm) * 8 + gg] - m4);
        rr[256 + tid] = s;
        __syncthreads();
        if (blockIdx.x == 0) {
            float stot = rr[256 + row * 4] + rr[256 + row * 4 + 1]
                       + rr[256 + row * 4 + 2] + rr[256 + row * 4 + 3];
            float inv = 1.f / stot;
            for (int mm = 0; mm < 32; ++mm)
                bmG[(m0 + mm) * 64 + c * 8 + gg] =
                    expf(lamB[(c * 128 + m0 + mm) * 8 + gg] - m4) * inv;
        }
    }
    for (int col = tid; col < 192; col += 256) {          // A softmax over i
        int j = col / 24; int rem = col - j * 24; int p = rem >> 3; int gg = rem & 7;
        float v[8]; float mx = -1e30f;
        #pragma unroll
        for (int i = 0; i < 8; ++i) {
            v[i] = lamA[((i * 8 + j) * 3 + p) * 8 + gg];
            mx = fmaxf(mx, v[i]);
        }
        float s = 0.f;
        #pragma unroll
        for (int i = 0; i < 8; ++i) { v[i] = expf(v[i] - mx); s += v[i]; }
        float inv = 1.f / s;
        #pragma unroll
        for (int i = 0; i < 8; ++i) {
            int idx = ((i * 8 + j) * 3 + p) * 8 + gg;
            float sm = v[i] * inv;
            sA[idx]   = sm;
            sALA[idx] = sm * logf(sm);
        }
    }
    for (int col = tid; col < 24; col += 256) {           // Pi softmax over c
        int p = col >> 3; int gg = col & 7;
        float v[8]; float mx = -1e30f;
        #pragma unroll
        for (int c = 0; c < 8; ++c) {
            v[c] = lamPi[(c * 3 + p) * 8 + gg];
            mx = fmaxf(mx, v[c]);
        }
        float s = 0.f;
        #pragma unroll
        for (int c = 0; c < 8; ++c) { v[c] = expf(v[c] - mx); s += v[c]; }
        float inv = 1.f / s;
        #pragma unroll
        for (int c = 0; c < 8; ++c) {
            int idx = (c * 3 + p) * 8 + gg;
            float sm = v[c] * inv;
            sPi[idx]  = sm;
            sLPi[idx] = logf(sm);
        }
    }
    if (tid < 8) {                                        // SP softmax over p
        int gg = tid;
        float v0 = lamSP[gg], v1 = lamSP[8 + gg], v2 = lamSP[16 + gg];
        float mx = fmaxf(v0, fmaxf(v1, v2));
        float e0 = expf(v0 - mx), e1 = expf(v1 - mx), e2 = expf(v2 - mx);
        float inv = 1.f / (e0 + e1 + e2);
        sSP[gg] = e0 * inv; sSP[8 + gg] = e1 * inv; sSP[16 + gg] = e2 * inv;
        sLSP[gg] = logf(e0 * inv); sLSP[8 + gg] = logf(e1 * inv); sLSP[16 + gg] = logf(e2 * inv);
    }
    gbar(&sync[1], tid);

    const float* pBm = bmG;
    const int id = blockIdx.x * 4 + w, t = id / 27, q = id % 27, xb = t * kNPT;
    float* bw = &bW[w][0];
    unsigned char* xw = &xW[w][0];

    // ================= phase 1: subtree up-pass =================
    for (int u = lane; u < 121; u += 64) {
        int gx;
        if (u == 0)       gx = 13 + q;
        else if (u < 4)   gx = 40  + q * 3  + (u - 1);
        else if (u < 13)  gx = 121 + q * 9  + (u - 4);
        else if (u < 40)  gx = 364 + q * 27 + (u - 13);
        else              gx = 1093 + q * 81 + (u - 40);
        xw[u] = (unsigned char)x[xb + gx];
    }
    __builtin_amdgcn_wave_barrier();

    for (int e = 3; e >= 0; --e) {
        int cnt = P3[e];
        for (int base = 0; base < cnt; base += 8) {
            int pi = base + n;
            if (pi < cnt) {
                float acc[8];
                #pragma unroll
                for (int i = 0; i < 8; ++i) acc[i] = 0.f;
                #pragma unroll
                for (int k = 0; k < 3; ++k) {
                    float bj[8];
                    if (e == 3) {
                        leaf_beta(sPi, pBm, k, xw[40 + 3 * pi + k], g, bj);
                    } else {
                        int co = (LO[e + 1] + 3 * pi + k) * kRS + g;
                        #pragma unroll
                        for (int j = 0; j < 8; ++j) bj[j] = bw[co + j * 8];
                    }
                    float spg = sSP[k * 8 + g];
                    #pragma unroll
                    for (int i = 0; i < 8; ++i) {
                        float s = 0.f;
                        #pragma unroll
                        for (int j = 0; j < 8; ++j)
                            s = fmaf(sA[((i * 8 + j) * 3 + k) * 8 + g], bj[j], s);
                        acc[i] = fmaf(spg, s, acc[i]);
                    }
                }
                if (e == 0) {
                    #pragma unroll
                    for (int i = 0; i < 8; ++i) bw[i * 8 + g] = acc[i];  // raw tb root
                    int xv = xw[0];
                    float s = 0.f;
                    #pragma unroll
                    for (int i = 0; i < 8; ++i) { acc[i] *= pBm[xv * 64 + i * 8 + g]; s += acc[i]; }
                    float ig = __builtin_amdgcn_rcpf(s);
                    #pragma unroll
                    for (int i = 0; i < 8; ++i) b3[id * 64 + i * 8 + g] = acc[i] * ig;
                } else {
                    int slot = LO[e] + pi;
                    int xv = xw[slot];
                    float s = 0.f;
                    #pragma unroll
                    for (int i = 0; i < 8; ++i) { acc[i] *= pBm[xv * 64 + i * 8 + g]; s += acc[i]; }
                    float ig = __builtin_amdgcn_rcpf(s);
                    int bo = slot * kRS + g;
                    #pragma unroll
                    for (int i = 0; i < 8; ++i) bw[bo + i * 8] = acc[i] * ig;
                    bw[slot * kRS + 64 + g] = s;
                }
            }
        }
        __builtin_amdgcn_wave_barrier();
    }
    gbar(&sync[2], tid);

    // ================= phase 2: mid (levels 0-3), one wave per tree ==========
    if (q == 0) {
        float ellm = 0.f;
        for (int f = 2; f >= 0; --f) {
            int cnt = (f == 2) ? 9 : (f == 1 ? 3 : 1);
            int pl0 = (f == 2) ? 4 : (f == 1 ? 1 : 0);
            int cl0 = (f == 1) ? 4 : 1;
            for (int base = 0; base < cnt; base += 8) {
                int pi = base + n;
                if (pi < cnt) {
                    float acc[8];
                    #pragma unroll
                    for (int i = 0; i < 8; ++i) acc[i] = 0.f;
                    #pragma unroll
                    for (int k = 0; k < 3; ++k) {
                        float bj[8];
                        if (f == 2) {
                            const float* src = b3 + (t * 27 + 3 * pi + k) * 64 + g;
                            #pragma unroll
                            for (int j = 0; j < 8; ++j) bj[j] = src[j * 8];
                        } else {
                            int co = (cl0 + 3 * pi + k) * kRS + g;
                            #pragma unroll
                            for (int j = 0; j < 8; ++j) bj[j] = bMid[co + j * 8];
                        }
                        float spg = sSP[k * 8 + g];
                        #pragma unroll
                        for (int i = 0; i < 8; ++i) {
                            float s = 0.f;
                            #pragma unroll
                            for (int j = 0; j < 8; ++j)
                                s = fmaf(sA[((i * 8 + j) * 3 + k) * 8 + g], bj[j], s);
                            acc[i] = fmaf(spg, s, acc[i]);
                        }
                    }
                    int slot = pl0 + pi;
                    int xv = x[xb + slot];
                    float s = 0.f;
                    #pragma unroll
                    for (int i = 0; i < 8; ++i) { acc[i] *= pBm[xv * 64 + i * 8 + g]; s += acc[i]; }
                    float ig = __builtin_amdgcn_rcpf(s);
                    int bo = slot * kRS + g;
                    #pragma unroll
                    for (int i = 0; i < 8; ++i) bMid[bo + i * 8] = acc[i] * ig;
                    bMid[slot * kRS + 64 + g] = s;
                }
            }
            __builtin_amdgcn_wave_barrier();
        }
        if (n == 0) {     // root: ell Bm term; slot0 := r = Bm/s
            int xv = x[xb];
            float invs = __builtin_amdgcn_rcpf(bMid[64 + g]);
            #pragma unroll
            for (int c = 0; c < 8; ++c)
                ellm += bMid[c * 8 + g] * pBm[xv * 64 + c * 8 + g];
            #pragma unroll
            for (int c = 0; c < 8; ++c)
                bMid[c * 8 + g] = pBm[xv * 64 + c * 8 + g] * invs;
        }
        __builtin_amdgcn_wave_barrier();
        for (int f = 1; f <= 3; ++f) {
            int cnt = (f == 1) ? 3 : (f == 2 ? 9 : 27);
            int cl0 = (f == 1) ? 1 : (f == 2 ? 4 : 13);
            int pl0 = (f == 1) ? 0 : (f == 2 ? 1 : 4);
            for (int base = 0; base < cnt; base += 8) {
                int ci = base + n;
                if (ci < cnt) {
                    int p = ci % 3;
                    int ps = (pl0 + ci / 3) * kRS + g;
                    float r[8];
                    #pragma unroll
                    for (int i = 0; i < 8; ++i) r[i] = bMid[ps + i * 8];
                    float bj[8]; float sv = 0.f;
                    if (f == 3) {
                        const float* src = b3 + (t * 27 + ci) * 64 + g;
                        #pragma unroll
                        for (int j = 0; j < 8; ++j) bj[j] = src[j * 8];
                    } else {
                        int co = (cl0 + ci) * kRS + g;
                        #pragma unroll
                        for (int j = 0; j < 8; ++j) bj[j] = bMid[co + j * 8];
                        sv = bMid[(cl0 + ci) * kRS + 64 + g];
                    }
                    float spg = sSP[p * 8 + g];
                    float esum = 0.f, lg = 0.f;
                    float ev[8];
                    #pragma unroll
                    for (int j = 0; j < 8; ++j) {
                        float s1 = 0.f, s2 = 0.f;
                        #pragma unroll
                        for (int i = 0; i < 8; ++i) {
                            int ai = ((i * 8 + j) * 3 + p) * 8 + g;
                            s1 = fmaf(r[i], sA[ai],   s1);
                            s2 = fmaf(r[i], sALA[ai], s2);
                        }
                        float bs = spg * bj[j];
                        ev[j] = bs * s1;
                        lg    = fmaf(bs, s2, lg);
                        esum += ev[j];
                    }
                    lg = fmaf(esum, sLSP[p * 8 + g], lg);
                    int xv = x[xb + cl0 + ci];
                    float Bmv[8];
                    #pragma unroll
                    for (int c = 0; c < 8; ++c) {
                        Bmv[c] = pBm[xv * 64 + c * 8 + g];
                        lg = fmaf(ev[c], Bmv[c], lg);
                    }
                    if (f == 3) {
                        #pragma unroll
                        for (int j = 0; j < 8; ++j)
                            e3[(t * 27 + ci) * 64 + j * 8 + g] = ev[j];
                    } else {
                        int co = (cl0 + ci) * kRS + g;
                        #pragma unroll
                        for (int j = 0; j < 8; ++j)
                            bMid[co + j * 8] = ev[j] * Bmv[j]
                                * __builtin_amdgcn_rcpf(bj[j] * sv);
                    }
                    ellm += lg;
                }
            }
            __builtin_amdgcn_wave_barrier();
        }
        ellm += __shfl_xor(ellm, 8);
        ellm += __shfl_xor(ellm, 16);
        ellm += __shfl_xor(ellm, 32);
        if (n == 0) out[t * 8 + g] = -ellm;      // initializes poisoned out
    }
    gbar(&sync[3], tid);

    // ================= phase 3: subtree down-pass =================
    bw[lane] = e3[id * 64 + lane] * __builtin_amdgcn_rcpf(bw[lane]);  // root r
    __builtin_amdgcn_wave_barrier();

    float ell = 0.f;
    for (int e = 1; e <= 4; ++e) {
        int cnt = P3[e], pl0 = LO[e - 1];
        for (int base = 0; base < cnt; base += 8) {
            int ci = base + n;
            if (ci < cnt) {
                int p = ci % 3;
                int ps = (pl0 + ci / 3) * kRS + g;
                float r[8];
                #pragma unroll
                for (int i = 0; i < 8; ++i) r[i] = bw[ps + i * 8];
                float bj[8]; float sv = 0.f;
                int xv;
                if (e == 4) {
                    xv = xw[40 + ci];
                    leaf_beta(sPi, pBm, p, xv, g, bj);
                } else {
                    int slot = LO[e] + ci;
                    xv = xw[slot];
                    int co = slot * kRS + g;
                    #pragma unroll
                    for (int j = 0; j < 8; ++j) bj[j] = bw[co + j * 8];
                    sv = bw[slot * kRS + 64 + g];
                }
                float spg = sSP[p * 8 + g];
                float esum = 0.f, lg = 0.f;
                float ev[8];
                #pragma unroll
                for (int j = 0; j < 8; ++j) {
                    float s1 = 0.f, s2 = 0.f;
                    #pragma unroll
                    for (int i = 0; i < 8; ++i) {
                        int ai = ((i * 8 + j) * 3 + p) * 8 + g;
                        s1 = fmaf(r[i], sA[ai],   s1);
                        s2 = fmaf(r[i], sALA[ai], s2);
                    }
                    float bs = spg * bj[j];
                    ev[j] = bs * s1;
                    lg    = fmaf(bs, s2, lg);
                    esum += ev[j];
                }
                lg = fmaf(esum, sLSP[p * 8 + g], lg);
                float Bmv[8];
                #pragma unroll
                for (int c = 0; c < 8; ++c) {
                    Bmv[c] = pBm[xv * 64 + c * 8 + g];
                    lg = fmaf(ev[c], Bmv[c], lg);
                }
                if (e < 4) {
                    int slot = LO[e] + ci;
                    int co = slot * kRS + g;
                    #pragma unroll
                    for (int j = 0; j < 8; ++j)
                        bw[co + j * 8] = ev[j] * Bmv[j]
                            * __builtin_amdgcn_rcpf(bj[j] * sv);
                } else {
                    #pragma unroll
                    for (int c = 0; c < 8; ++c)
                        lg = fmaf(ev[c], sLPi[(c * 3 + p) * 8 + g], lg);
                }
                ell += lg;
            }
        }
        __builtin_amdgcn_wave_barrier();
    }

    ell += __shfl_xor(ell, 8);
    ell += __shfl_xor(ell, 16);
    ell += __shfl_xor(ell, 32);
    if (n == 0) atomicAdd(&out[t * 8 + g], -ell);
}

} // namespace

extern "C" void kernel_launch(void* const* d_in, const int* in_sizes, int n_in,
                              void* d_out, int out_size, void* d_ws, size_t ws_size,
                              hipStream_t stream) {
    const float* lamA  = (const float*)d_in[0];
    const float* lamB  = (const float*)d_in[1];
    const float* lamPi = (const float*)d_in[2];
    const float* lamSP = (const float*)d_in[3];
    const int*   x     = (const int*)d_in[4];
    float* out = (float*)d_out;
    unsigned* sync = (unsigned*)d_ws;       // [0]=flag, [1..3]=barrier counters
    float* bmG = (float*)d_ws + 512;        // 2KB away from sync; 8192 floats
    float* b3  = bmG + 8192;                // 1728*64
    float* e3  = b3 + 1728 * 64;            // 1728*64

    fused<<<dim3(432), dim3(256), 0, stream>>>(
        lamA, lamB, lamPi, lamSP, x, out, sync, bmG, b3, e3);
}

// Round 9
// 156.635 us; speedup vs baseline: 2.0778x; 1.5011x over previous
//
#include <hip/hip_runtime.h>

// PosteriorHiddenTreeMarkovModel — MI355X / gfx950
// R9: per-tree wave-level sync, zero steady-state fences.
// R8's grid barriers cost ~100us: each of 4 gbars made 432 blocks run
// __threadfence (full L2 wbl2 + L1/L2 inv) and convoy on the grid straggler.
// Fix: cross-phase globals (b3,e3) use agent-scope RELAXED atomic load/store
// (coherence-point I/O, no wbl2/inv needed); sync = 64 per-tree counters
// (27 subtree waves fetch_add after b3) + per-tree flags (mid sets after e3);
// waves poll independently -> trees pipeline, no convoy. Ordering = wave-local
// s_waitcnt(0) before each signal. Single __threadfence per block, once, after
// the Bm-publication gate (also invalidates stale poison lines for cached bmG
// reads). Mid's ell goes through atomicAdd (coherence-point RMW, no fence).
// Co-residency: LDS 63KB -> 2 blocks/CU x 256 = 512 >= 432 blocks resident.

namespace {

constexpr int kNPT = 3280;
constexpr int kRS  = 72;   // record stride: 64 beta + 8 pre-norm sums s
constexpr unsigned kMAGIC  = 0x13579BDFu;
constexpr unsigned kMAGIC2 = 0x2468ACEFu;
__device__ __constant__ int LO[6] = {0, 1, 4, 13, 40, 121};
__device__ __constant__ int P3[5] = {1, 3, 9, 27, 81};

#define AGENT_LD(p)    __hip_atomic_load((p), __ATOMIC_RELAXED, __HIP_MEMORY_SCOPE_AGENT)
#define AGENT_ST(p, v) __hip_atomic_store((p), (v), __ATOMIC_RELAXED, __HIP_MEMORY_SCOPE_AGENT)

__device__ __forceinline__ void leaf_beta(const float* __restrict__ sPi,
                                          const float* __restrict__ pBm,
                                          int p, int xv, int g, float* b)
{
    float s = 0.f;
    #pragma unroll
    for (int c = 0; c < 8; ++c) {
        b[c] = sPi[(c * 3 + p) * 8 + g] * pBm[xv * 64 + c * 8 + g];
        s += b[c];
    }
    float ig = __builtin_amdgcn_rcpf(s);
    #pragma unroll
    for (int c = 0; c < 8; ++c) b[c] *= ig;
}

__global__ __launch_bounds__(256, 2)
void fused(const float* __restrict__ lamA, const float* __restrict__ lamB,
           const float* __restrict__ lamPi, const float* __restrict__ lamSP,
           const int* __restrict__ x, float* __restrict__ out,
           unsigned* __restrict__ sy, float* __restrict__ bmG,
           float* __restrict__ b3, float* __restrict__ e3)
{
    const int tid = threadIdx.x, w = tid >> 6, lane = tid & 63;
    const int n = lane >> 3, g = lane & 7;
    __shared__ float sA[1536], sALA[1536], sPi[192], sLPi[192], sSP[24], sLSP[24];
    __shared__ float bW[4][40 * kRS];      // per-wave subtree records
    __shared__ float bMid[13 * kRS];       // mid records (one mid wave/block max)
    __shared__ unsigned char xW[4][124];
    // sy layout: [0]=magic gate, [4]=bm flag, [32+t*32]=tree counter,
    //            [2080+t*32]=tree flag
    unsigned* trCnt = sy + 32;
    unsigned* trFlg = sy + 2080;

    // ---- init gate: block0 zeroes 64 tree counters, publishes magic ----
    if (tid == 0) {
        if (blockIdx.x == 0) {
            for (int i = 0; i < 64; ++i) AGENT_ST(&trCnt[i * 32], 0u);
            __builtin_amdgcn_s_waitcnt(0);
            AGENT_ST(&sy[0], kMAGIC);
        }
        unsigned long sp = 0;
        while (AGENT_LD(&sy[0]) != kMAGIC) {
            if (++sp > (1UL << 24)) break;
            __builtin_amdgcn_s_sleep(2);
        }
    }
    __syncthreads();

    // ================= phase 0: parameters =================
    if (blockIdx.x == 0) {   // Bm softmax -> bmG (transposed [m][c][g]) + flag
        float* rr = &bW[0][0];
        int row = tid >> 2, part = tid & 3;
        int c = row >> 3, gg = row & 7, m0 = part * 32;
        float mx = -1e30f;
        for (int mm = 0; mm < 32; ++mm)
            mx = fmaxf(mx, lamB[(c * 128 + m0 + mm) * 8 + gg]);
        rr[tid] = mx;
        __syncthreads();
        float m4 = fmaxf(fmaxf(rr[row * 4], rr[row * 4 + 1]),
                         fmaxf(rr[row * 4 + 2], rr[row * 4 + 3]));
        float s = 0.f;
        for (int mm = 0; mm < 32; ++mm)
            s += expf(lamB[(c * 128 + m0 + mm) * 8 + gg] - m4);
        rr[256 + tid] = s;
        __syncthreads();
        float stot = rr[256 + row * 4] + rr[256 + row * 4 + 1]
                   + rr[256 + row * 4 + 2] + rr[256 + row * 4 + 3];
        float inv = 1.f / stot;
        for (int mm = 0; mm < 32; ++mm)
            AGENT_ST(&bmG[(m0 + mm) * 64 + c * 8 + gg],
                     expf(lamB[(c * 128 + m0 + mm) * 8 + gg] - m4) * inv);
        __syncthreads();                       // all stores drained (waitcnt)
        if (tid == 0) AGENT_ST(&sy[4], kMAGIC2);
    }
    for (int col = tid; col < 192; col += 256) {          // A softmax over i
        int j = col / 24; int rem = col - j * 24; int p = rem >> 3; int gg = rem & 7;
        float v[8]; float mx = -1e30f;
        #pragma unroll
        for (int i = 0; i < 8; ++i) {
            v[i] = lamA[((i * 8 + j) * 3 + p) * 8 + gg];
            mx = fmaxf(mx, v[i]);
        }
        float s = 0.f;
        #pragma unroll
        for (int i = 0; i < 8; ++i) { v[i] = expf(v[i] - mx); s += v[i]; }
        float inv = 1.f / s;
        #pragma unroll
        for (int i = 0; i < 8; ++i) {
            int idx = ((i * 8 + j) * 3 + p) * 8 + gg;
            float sm = v[i] * inv;
            sA[idx]   = sm;
            sALA[idx] = sm * logf(sm);
        }
    }
    for (int col = tid; col < 24; col += 256) {           // Pi softmax over c
        int p = col >> 3; int gg = col & 7;
        float v[8]; float mx = -1e30f;
        #pragma unroll
        for (int c = 0; c < 8; ++c) {
            v[c] = lamPi[(c * 3 + p) * 8 + gg];
            mx = fmaxf(mx, v[c]);
        }
        float s = 0.f;
        #pragma unroll
        for (int c = 0; c < 8; ++c) { v[c] = expf(v[c] - mx); s += v[c]; }
        float inv = 1.f / s;
        #pragma unroll
        for (int c = 0; c < 8; ++c) {
            int idx = (c * 3 + p) * 8 + gg;
            float sm = v[c] * inv;
            sPi[idx]  = sm;
            sLPi[idx] = logf(sm);
        }
    }
    if (tid < 8) {                                        // SP softmax over p
        int gg = tid;
        float v0 = lamSP[gg], v1 = lamSP[8 + gg], v2 = lamSP[16 + gg];
        float mx = fmaxf(v0, fmaxf(v1, v2));
        float e0 = expf(v0 - mx), e1 = expf(v1 - mx), e2 = expf(v2 - mx);
        float inv = 1.f / (e0 + e1 + e2);
        sSP[gg] = e0 * inv; sSP[8 + gg] = e1 * inv; sSP[16 + gg] = e2 * inv;
        sLSP[gg] = logf(e0 * inv); sLSP[8 + gg] = logf(e1 * inv); sLSP[16 + gg] = logf(e2 * inv);
    }
    // Bm gate: one fence per block per launch (also invalidates stale poison
    // lines so cached bmG reads below are safe).
    if (tid == 0) {
        unsigned long sp = 0;
        while (AGENT_LD(&sy[4]) != kMAGIC2) {
            if (++sp > (1UL << 24)) break;
            __builtin_amdgcn_s_sleep(2);
        }
        __threadfence();
    }
    __syncthreads();

    const float* pBm = bmG;
    const int id = blockIdx.x * 4 + w, t = id / 27, q = id % 27, xb = t * kNPT;
    float* bw = &bW[w][0];
    unsigned char* xw = &xW[w][0];

    // ================= phase 1: subtree up-pass =================
    for (int u = lane; u < 121; u += 64) {
        int gx;
        if (u == 0)       gx = 13 + q;
        else if (u < 4)   gx = 40  + q * 3  + (u - 1);
        else if (u < 13)  gx = 121 + q * 9  + (u - 4);
        else if (u < 40)  gx = 364 + q * 27 + (u - 13);
        else              gx = 1093 + q * 81 + (u - 40);
        xw[u] = (unsigned char)x[xb + gx];
    }
    __builtin_amdgcn_wave_barrier();

    for (int e = 3; e >= 0; --e) {
        int cnt = P3[e];
        for (int base = 0; base < cnt; base += 8) {
            int pi = base + n;
            if (pi < cnt) {
                float acc[8];
                #pragma unroll
                for (int i = 0; i < 8; ++i) acc[i] = 0.f;
                #pragma unroll
                for (int k = 0; k < 3; ++k) {
                    float bj[8];
                    if (e == 3) {
                        leaf_beta(sPi, pBm, k, xw[40 + 3 * pi + k], g, bj);
                    } else {
                        int co = (LO[e + 1] + 3 * pi + k) * kRS + g;
                        #pragma unroll
                        for (int j = 0; j < 8; ++j) bj[j] = bw[co + j * 8];
                    }
                    float spg = sSP[k * 8 + g];
                    #pragma unroll
                    for (int i = 0; i < 8; ++i) {
                        float s = 0.f;
                        #pragma unroll
                        for (int j = 0; j < 8; ++j)
                            s = fmaf(sA[((i * 8 + j) * 3 + k) * 8 + g], bj[j], s);
                        acc[i] = fmaf(spg, s, acc[i]);
                    }
                }
                if (e == 0) {
                    #pragma unroll
                    for (int i = 0; i < 8; ++i) bw[i * 8 + g] = acc[i];  // raw tb root
                    int xv = xw[0];
                    float s = 0.f;
                    #pragma unroll
                    for (int i = 0; i < 8; ++i) { acc[i] *= pBm[xv * 64 + i * 8 + g]; s += acc[i]; }
                    float ig = __builtin_amdgcn_rcpf(s);
                    #pragma unroll
                    for (int i = 0; i < 8; ++i)
                        AGENT_ST(&b3[id * 64 + i * 8 + g], acc[i] * ig);
                } else {
                    int slot = LO[e] + pi;
                    int xv = xw[slot];
                    float s = 0.f;
                    #pragma unroll
                    for (int i = 0; i < 8; ++i) { acc[i] *= pBm[xv * 64 + i * 8 + g]; s += acc[i]; }
                    float ig = __builtin_amdgcn_rcpf(s);
                    int bo = slot * kRS + g;
                    #pragma unroll
                    for (int i = 0; i < 8; ++i) bw[bo + i * 8] = acc[i] * ig;
                    bw[slot * kRS + 64 + g] = s;
                }
            }
        }
        __builtin_amdgcn_wave_barrier();
    }
    // signal: this subtree's b3 is at the coherence point
    __builtin_amdgcn_s_waitcnt(0);
    if (lane == 0)
        __hip_atomic_fetch_add(&trCnt[t * 32], 1u, __ATOMIC_RELAXED,
                               __HIP_MEMORY_SCOPE_AGENT);

    // ================= phase 2: mid (levels 0-3), q==0 wave per tree =========
    if (q == 0) {
        unsigned long sp = 0;
        while (AGENT_LD(&trCnt[t * 32]) < 27u) {          // all lanes, same addr
            if (++sp > (1UL << 22)) break;
            __builtin_amdgcn_s_sleep(1);
        }
        float ellm = 0.f;
        for (int f = 2; f >= 0; --f) {
            int cnt = (f == 2) ? 9 : (f == 1 ? 3 : 1);
            int pl0 = (f == 2) ? 4 : (f == 1 ? 1 : 0);
            int cl0 = (f == 1) ? 4 : 1;
            for (int base = 0; base < cnt; base += 8) {
                int pi = base + n;
                if (pi < cnt) {
                    float acc[8];
                    #pragma unroll
                    for (int i = 0; i < 8; ++i) acc[i] = 0.f;
                    #pragma unroll
                    for (int k = 0; k < 3; ++k) {
                        float bj[8];
                        if (f == 2) {
                            float* src = b3 + (t * 27 + 3 * pi + k) * 64 + g;
                            #pragma unroll
                            for (int j = 0; j < 8; ++j) bj[j] = AGENT_LD(&src[j * 8]);
                        } else {
                            int co = (cl0 + 3 * pi + k) * kRS + g;
                            #pragma unroll
                            for (int j = 0; j < 8; ++j) bj[j] = bMid[co + j * 8];
                        }
                        float spg = sSP[k * 8 + g];
                        #pragma unroll
                        for (int i = 0; i < 8; ++i) {
                            float s = 0.f;
                            #pragma unroll
                            for (int j = 0; j < 8; ++j)
                                s = fmaf(sA[((i * 8 + j) * 3 + k) * 8 + g], bj[j], s);
                            acc[i] = fmaf(spg, s, acc[i]);
                        }
                    }
                    int slot = pl0 + pi;
                    int xv = x[xb + slot];
                    float s = 0.f;
                    #pragma unroll
                    for (int i = 0; i < 8; ++i) { acc[i] *= pBm[xv * 64 + i * 8 + g]; s += acc[i]; }
                    float ig = __builtin_amdgcn_rcpf(s);
                    int bo = slot * kRS + g;
                    #pragma unroll
                    for (int i = 0; i < 8; ++i) bMid[bo + i * 8] = acc[i] * ig;
                    bMid[slot * kRS + 64 + g] = s;
                }
            }
            __builtin_amdgcn_wave_barrier();
        }
        if (n == 0) {     // root: ell Bm term; slot0 := r = Bm/s
            int xv = x[xb];
            float invs = __builtin_amdgcn_rcpf(bMid[64 + g]);
            #pragma unroll
            for (int c = 0; c < 8; ++c)
                ellm += bMid[c * 8 + g] * pBm[xv * 64 + c * 8 + g];
            #pragma unroll
            for (int c = 0; c < 8; ++c)
                bMid[c * 8 + g] = pBm[xv * 64 + c * 8 + g] * invs;
        }
        __builtin_amdgcn_wave_barrier();
        for (int f = 1; f <= 3; ++f) {
            int cnt = (f == 1) ? 3 : (f == 2 ? 9 : 27);
            int cl0 = (f == 1) ? 1 : (f == 2 ? 4 : 13);
            int pl0 = (f == 1) ? 0 : (f == 2 ? 1 : 4);
            for (int base = 0; base < cnt; base += 8) {
                int ci = base + n;
                if (ci < cnt) {
                    int p = ci % 3;
                    int ps = (pl0 + ci / 3) * kRS + g;
                    float r[8];
                    #pragma unroll
                    for (int i = 0; i < 8; ++i) r[i] = bMid[ps + i * 8];
                    float bj[8]; float sv = 0.f;
                    if (f == 3) {
                        float* src = b3 + (t * 27 + ci) * 64 + g;
                        #pragma unroll
                        for (int j = 0; j < 8; ++j) bj[j] = AGENT_LD(&src[j * 8]);
                    } else {
                        int co = (cl0 + ci) * kRS + g;
                        #pragma unroll
                        for (int j = 0; j < 8; ++j) bj[j] = bMid[co + j * 8];
                        sv = bMid[(cl0 + ci) * kRS + 64 + g];
                    }
                    float spg = sSP[p * 8 + g];
                    float esum = 0.f, lg = 0.f;
                    float ev[8];
                    #pragma unroll
                    for (int j = 0; j < 8; ++j) {
                        float s1 = 0.f, s2 = 0.f;
                        #pragma unroll
                        for (int i = 0; i < 8; ++i) {
                            int ai = ((i * 8 + j) * 3 + p) * 8 + g;
                            s1 = fmaf(r[i], sA[ai],   s1);
                            s2 = fmaf(r[i], sALA[ai], s2);
                        }
                        float bs = spg * bj[j];
                        ev[j] = bs * s1;
                        lg    = fmaf(bs, s2, lg);
                        esum += ev[j];
                    }
                    lg = fmaf(esum, sLSP[p * 8 + g], lg);
                    int xv = x[xb + cl0 + ci];
                    float Bmv[8];
                    #pragma unroll
                    for (int c = 0; c < 8; ++c) {
                        Bmv[c] = pBm[xv * 64 + c * 8 + g];
                        lg = fmaf(ev[c], Bmv[c], lg);
                    }
                    if (f == 3) {
                        #pragma unroll
                        for (int j = 0; j < 8; ++j)
                            AGENT_ST(&e3[(t * 27 + ci) * 64 + j * 8 + g], ev[j]);
                    } else {
                        int co = (cl0 + ci) * kRS + g;
                        #pragma unroll
                        for (int j = 0; j < 8; ++j)
                            bMid[co + j * 8] = ev[j] * Bmv[j]
                                * __builtin_amdgcn_rcpf(bj[j] * sv);
                    }
                    ellm += lg;
                }
            }
            __builtin_amdgcn_wave_barrier();
        }
        ellm += __shfl_xor(ellm, 8);
        ellm += __shfl_xor(ellm, 16);
        ellm += __shfl_xor(ellm, 32);
        if (n == 0) atomicAdd(&out[t * 8 + g], -ellm);
        __builtin_amdgcn_s_waitcnt(0);                    // e3 at coherence point
        if (lane == 0) AGENT_ST(&trFlg[t * 32], kMAGIC2);
    }

    // ================= phase 3: subtree down-pass =================
    {
        unsigned long sp = 0;
        while (AGENT_LD(&trFlg[t * 32]) != kMAGIC2) {     // all lanes, same addr
            if (++sp > (1UL << 22)) break;
            __builtin_amdgcn_s_sleep(1);
        }
    }
    bw[lane] = AGENT_LD(&e3[id * 64 + lane]) * __builtin_amdgcn_rcpf(bw[lane]);
    __builtin_amdgcn_wave_barrier();

    float ell = 0.f;
    for (int e = 1; e <= 4; ++e) {
        int cnt = P3[e], pl0 = LO[e - 1];
        for (int base = 0; base < cnt; base += 8) {
            int ci = base + n;
            if (ci < cnt) {
                int p = ci % 3;
                int ps = (pl0 + ci / 3) * kRS + g;
                float r[8];
                #pragma unroll
                for (int i = 0; i < 8; ++i) r[i] = bw[ps + i * 8];
                float bj[8]; float sv = 0.f;
                int xv;
                if (e == 4) {
                    xv = xw[40 + ci];
                    leaf_beta(sPi, pBm, p, xv, g, bj);
                } else {
                    int slot = LO[e] + ci;
                    xv = xw[slot];
                    int co = slot * kRS + g;
                    #pragma unroll
                    for (int j = 0; j < 8; ++j) bj[j] = bw[co + j * 8];
                    sv = bw[slot * kRS + 64 + g];
                }
                float spg = sSP[p * 8 + g];
                float esum = 0.f, lg = 0.f;
                float ev[8];
                #pragma unroll
                for (int j = 0; j < 8; ++j) {
                    float s1 = 0.f, s2 = 0.f;
                    #pragma unroll
                    for (int i = 0; i < 8; ++i) {
                        int ai = ((i * 8 + j) * 3 + p) * 8 + g;
                        s1 = fmaf(r[i], sA[ai],   s1);
                        s2 = fmaf(r[i], sALA[ai], s2);
                    }
                    float bs = spg * bj[j];
                    ev[j] = bs * s1;
                    lg    = fmaf(bs, s2, lg);
                    esum += ev[j];
                }
                lg = fmaf(esum, sLSP[p * 8 + g], lg);
                float Bmv[8];
                #pragma unroll
                for (int c = 0; c < 8; ++c) {
                    Bmv[c] = pBm[xv * 64 + c * 8 + g];
                    lg = fmaf(ev[c], Bmv[c], lg);
                }
                if (e < 4) {
                    int slot = LO[e] + ci;
                    int co = slot * kRS + g;
                    #pragma unroll
                    for (int j = 0; j < 8; ++j)
                        bw[co + j * 8] = ev[j] * Bmv[j]
                            * __builtin_amdgcn_rcpf(bj[j] * sv);
                } else {
                    #pragma unroll
                    for (int c = 0; c < 8; ++c)
                        lg = fmaf(ev[c], sLPi[(c * 3 + p) * 8 + g], lg);
                }
                ell += lg;
            }
        }
        __builtin_amdgcn_wave_barrier();
    }

    ell += __shfl_xor(ell, 8);
    ell += __shfl_xor(ell, 16);
    ell += __shfl_xor(ell, 32);
    if (n == 0) atomicAdd(&out[t * 8 + g], -ell);
}

} // namespace

extern "C" void kernel_launch(void* const* d_in, const int* in_sizes, int n_in,
                              void* d_out, int out_size, void* d_ws, size_t ws_size,
                              hipStream_t stream) {
    const float* lamA  = (const float*)d_in[0];
    const float* lamB  = (const float*)d_in[1];
    const float* lamPi = (const float*)d_in[2];
    const float* lamSP = (const float*)d_in[3];
    const int*   x     = (const int*)d_in[4];
    float* out = (float*)d_out;
    unsigned* sy  = (unsigned*)d_ws;        // 8192 uints (32 KB) sync area
    float* bmG = (float*)d_ws + 8192;       // 8192 floats
    float* b3  = bmG + 8192;                // 1728*64
    float* e3  = b3 + 1728 * 64;            // 1728*64

    fused<<<dim3(432), dim3(256), 0, stream>>>(
        lamA, lamB, lamPi, lamSP, x, out, sy, bmG, b3, e3);
}